// Round 11
// baseline (346.119 us; speedup 1.0000x reference)
//
#include <hip/hip_runtime.h>
#include <hip/hip_bf16.h>

// GCN 2-layer encoder. CSR-gather aggregation + split-bf16 MFMA GEMMs.
// GEMM "occ": BM=32 (big grid), 4 waves 2x2, B-only LDS (GK=32, 20.5KB), A global->reg
// double-buffered with in-register hi/lo convert. Occupancy-first design.

typedef __attribute__((ext_vector_type(4))) float f32x4;
typedef __attribute__((ext_vector_type(8))) short short8;
typedef __attribute__((ext_vector_type(8))) unsigned short u16x8;

static __device__ __forceinline__ unsigned short f2bf(float f) {
    unsigned int u = __float_as_uint(f);
    u += 0x7FFF + ((u >> 16) & 1);          // round-to-nearest-even
    return (unsigned short)(u >> 16);
}
static __device__ __forceinline__ float bf2f(unsigned short h) {
    return __uint_as_float(((unsigned int)h) << 16);
}

__global__ void fill_int(int* __restrict__ p, int v, int n) {
    int i = blockIdx.x * blockDim.x + threadIdx.x;
    if (i < n) p[i] = v;
}

__global__ void deg_accum_i(const int* __restrict__ dst, int* __restrict__ deg, int E) {
    int i = blockIdx.x * blockDim.x + threadIdx.x;
    if (i < E) atomicAdd(&deg[dst[i]], 1);
}

__global__ void make_dis(int* __restrict__ deg, int N) {
    int i = blockIdx.x * blockDim.x + threadIdx.x;
    if (i < N) {
        int d = deg[i];
        ((float*)deg)[i] = rsqrtf((float)(d + 1));
    }
}

// ---- hierarchical exclusive scan: deg[N] -> rp[N+1], cursor[N] ----
__global__ void scan_part(const int* __restrict__ deg, int* __restrict__ bsum, int N) {
    int tid = threadIdx.x, lane = tid & 63, wid = tid >> 6;
    int i = blockIdx.x * 256 + tid;
    int v = (i < N) ? deg[i] : 0;
#pragma unroll
    for (int off = 1; off < 64; off <<= 1) v += __shfl_xor(v, off, 64);
    __shared__ int ws[4];
    if (lane == 0) ws[wid] = v;
    __syncthreads();
    if (tid == 0) bsum[blockIdx.x] = ws[0] + ws[1] + ws[2] + ws[3];
}

__global__ __launch_bounds__(1024) void scan_top(const int* __restrict__ bsum, int nb,
                                                 int* __restrict__ boff, int* __restrict__ rp, int N) {
    __shared__ int wsum[16];
    int tid = threadIdx.x, lane = tid & 63, wid = tid >> 6;
    int v = (tid < nb) ? bsum[tid] : 0;
    int x = v;
#pragma unroll
    for (int off = 1; off < 64; off <<= 1) {
        int t = __shfl_up(x, off, 64);
        if (lane >= off) x += t;
    }
    if (lane == 63) wsum[wid] = x;
    __syncthreads();
    if (tid < 16) {
        int y = wsum[tid];
#pragma unroll
        for (int off = 1; off < 16; off <<= 1) {
            int t = __shfl_up(y, off, 16);
            if (tid >= off) y += t;
        }
        wsum[tid] = y;
    }
    __syncthreads();
    int base = wid ? wsum[wid - 1] : 0;
    if (tid < nb) boff[tid] = base + x - v;
    if (tid == 0) rp[N] = wsum[15];
}

__global__ void scan_final(const int* __restrict__ deg, const int* __restrict__ boff,
                           int* __restrict__ rp, int* __restrict__ cursor, int N) {
    int tid = threadIdx.x, lane = tid & 63, wid = tid >> 6;
    int i = blockIdx.x * 256 + tid;
    int v = (i < N) ? deg[i] : 0;
    int x = v;
#pragma unroll
    for (int off = 1; off < 64; off <<= 1) {
        int t = __shfl_up(x, off, 64);
        if (lane >= off) x += t;
    }
    __shared__ int wsum[4];
    if (lane == 63) wsum[wid] = x;
    __syncthreads();
    int base = boff[blockIdx.x];
    for (int ww = 0; ww < wid; ww++) base += wsum[ww];
    int ex = base + x - v;
    if (i < N) { rp[i] = ex; cursor[i] = ex; }
}

__global__ void csr_fill(const int* __restrict__ src, const int* __restrict__ dst,
                         int* __restrict__ cursor, int* __restrict__ csr_src, int E) {
    int e = blockIdx.x * blockDim.x + threadIdx.x;
    if (e < E) {
        int pos = atomicAdd(&cursor[dst[e]], 1);
        csr_src[pos] = src[e];
    }
}

// B[K x N] f32 -> transposed bf16 hi/lo [N][Kpad] (zero-padded past K)
__global__ void prep_b(const float* __restrict__ B, unsigned short* __restrict__ Bth,
                       unsigned short* __restrict__ Btl, int K, int N, int Kpad) {
    int idx = blockIdx.x * 256 + threadIdx.x;
    if (idx >= N * Kpad) return;
    int n = idx / Kpad, k = idx - n * Kpad;
    float v = (k < K) ? B[(size_t)k * N + n] : 0.f;
    unsigned short h = f2bf(v);
    Bth[idx] = h;
    Btl[idx] = f2bf(v - bf2f(h));
}

// C[M x BN] = A[M x K] @ B[K x BN], split-bf16 MFMA, occupancy-first.
// BM=32; 4 waves = 2 rowgrp x 2 colgrp; wave tile 16 x (BN/2).
// B (preconverted bf16 hi/lo [BN][Kpad]) staged in LDS per 32-k group, single buffer.
// A: global->reg (2 float4/lane/group, double-buffered), hi/lo convert in registers.
template<int BN, int NG>
__global__ __launch_bounds__(256, 6) void gemm_occ(
    const float* __restrict__ A, const unsigned short* __restrict__ Bth,
    const unsigned short* __restrict__ Btl, float* __restrict__ C,
    int M, int K, int Kpad) {
    constexpr int GK = 32, STR = 40;
    constexpr int NF = BN / 2 / 16;          // col fragments per wave
    constexpr int TPC = 256 / BN;            // staging threads per B column
    constexpr int SPT = GK / TPC;            // ushorts per thread per plane
    constexpr int NVB = SPT / 8;             // u16x8 per thread per plane
    static_assert(NVB >= 1, "staging shape");

    __shared__ unsigned short BsH[BN][STR], BsL[BN][STR];

    const int tid = threadIdx.x, lane = tid & 63, w = tid >> 6;
    const int rowgrp = w >> 1, colgrp = w & 1;
    const int lrow = lane & 15, lkq = (lane >> 4) * 8;
    const int myrow = blockIdx.x * 32 + rowgrp * 16 + lrow;
    const bool aok = myrow < M;
    const float* aPtr = A + (size_t)myrow * K;
    const int wcol = colgrp * (BN / 2);

    const int sCol = tid / TPC;
    const int sKo = (tid % TPC) * SPT;
    const unsigned short* sbh = Bth + (size_t)sCol * Kpad + sKo;
    const unsigned short* sbl = Btl + (size_t)sCol * Kpad + sKo;

    f32x4 acc[NF] = {};
    float4 a0[2], a1[2];
    u16x8 rbh[NVB], rbl[NVB];

    auto LOADA = [&](float4 (&a)[2], int g) {
        const float4 z = make_float4(0.f, 0.f, 0.f, 0.f);
        int kg = g * GK + lkq;
        a[0] = (aok && kg + 4 <= K) ? *(const float4*)(aPtr + kg) : z;
        a[1] = (aok && kg + 8 <= K) ? *(const float4*)(aPtr + kg + 4) : z;
    };
    auto LOADB = [&](int g) {
#pragma unroll
        for (int v = 0; v < NVB; v++) {
            rbh[v] = *(const u16x8*)(sbh + g * GK + v * 8);
            rbl[v] = *(const u16x8*)(sbl + g * GK + v * 8);
        }
    };
    auto WRITEB = [&]() {
#pragma unroll
        for (int v = 0; v < NVB; v++) {
            *(u16x8*)&BsH[sCol][sKo + v * 8] = rbh[v];
            *(u16x8*)&BsL[sCol][sKo + v * 8] = rbl[v];
        }
    };
    auto TILE = [&](const float4 (&a)[2]) {
        float fv[8] = {a[0].x, a[0].y, a[0].z, a[0].w, a[1].x, a[1].y, a[1].z, a[1].w};
        short8 ah, al;
#pragma unroll
        for (int j = 0; j < 8; j++) {
            unsigned short hu = f2bf(fv[j]);
            ah[j] = (short)hu;
            al[j] = (short)f2bf(fv[j] - bf2f(hu));
        }
        short8 bh[NF], bl[NF];
#pragma unroll
        for (int n = 0; n < NF; n++) {
            bh[n] = *(const short8*)&BsH[wcol + n * 16 + lrow][lkq];
            bl[n] = *(const short8*)&BsL[wcol + n * 16 + lrow][lkq];
        }
#pragma unroll
        for (int n = 0; n < NF; n++)
            acc[n] = __builtin_amdgcn_mfma_f32_16x16x32_bf16(ah, bh[n], acc[n], 0, 0, 0);
#pragma unroll
        for (int n = 0; n < NF; n++)
            acc[n] = __builtin_amdgcn_mfma_f32_16x16x32_bf16(al, bh[n], acc[n], 0, 0, 0);
#pragma unroll
        for (int n = 0; n < NF; n++)
            acc[n] = __builtin_amdgcn_mfma_f32_16x16x32_bf16(ah, bl[n], acc[n], 0, 0, 0);
    };

    LOADB(0);
    LOADA(a0, 0);
    WRITEB();
    __syncthreads();
#pragma unroll
    for (int g = 0; g < NG; g++) {
        const bool more = (g + 1 < NG);
        if (more) {
            LOADB(g + 1);                       // L2-resident weights, in flight under MFMA
            if (g & 1) LOADA(a0, g + 1); else LOADA(a1, g + 1);
        }
        if (g & 1) TILE(a1); else TILE(a0);
        if (more) {
            __syncthreads();                    // all waves done reading Bs[g]
            WRITEB();
            __syncthreads();                    // Bs[g+1] visible
        }
    }

    // store: C/D layout col=lane&15, row=(lane>>4)*4+q
#pragma unroll
    for (int n = 0; n < NF; n++)
#pragma unroll
        for (int q = 0; q < 4; q++) {
            int row = blockIdx.x * 32 + rowgrp * 16 + (lane >> 4) * 4 + q;
            int col = wcol + n * 16 + lrow;
            if (row < M) C[(size_t)row * BN + col] = acc[n][q];
        }
}

// one wave per dst node, lanes across 128 features (float2/lane); fused self-loop+bias+relu
__global__ __launch_bounds__(256) void gather128(
    const int* __restrict__ rp, const int* __restrict__ csr,
    const float* __restrict__ dis, const float* __restrict__ h,
    const float* __restrict__ bias, float* __restrict__ out, int Nn) {
    int n = (blockIdx.x * 256 + threadIdx.x) >> 6;
    int lane = threadIdx.x & 63;
    if (n >= Nn) return;
    int beg = rp[n], end = rp[n + 1];
    float a0x = 0.f, a0y = 0.f, a1x = 0.f, a1y = 0.f;
    float a2x = 0.f, a2y = 0.f, a3x = 0.f, a3y = 0.f;
    int j = beg;
    for (; j + 3 < end; j += 4) {
        int s0 = csr[j], s1 = csr[j + 1], s2 = csr[j + 2], s3 = csr[j + 3];
        float w0 = dis[s0], w1 = dis[s1], w2 = dis[s2], w3 = dis[s3];
        float2 v0 = *(const float2*)&h[(size_t)s0 * 128 + lane * 2];
        float2 v1 = *(const float2*)&h[(size_t)s1 * 128 + lane * 2];
        float2 v2 = *(const float2*)&h[(size_t)s2 * 128 + lane * 2];
        float2 v3 = *(const float2*)&h[(size_t)s3 * 128 + lane * 2];
        a0x = fmaf(w0, v0.x, a0x); a0y = fmaf(w0, v0.y, a0y);
        a1x = fmaf(w1, v1.x, a1x); a1y = fmaf(w1, v1.y, a1y);
        a2x = fmaf(w2, v2.x, a2x); a2y = fmaf(w2, v2.y, a2y);
        a3x = fmaf(w3, v3.x, a3x); a3y = fmaf(w3, v3.y, a3y);
    }
    for (; j < end; j++) {
        int s = csr[j];
        float ww = dis[s];
        float2 v = *(const float2*)&h[(size_t)s * 128 + lane * 2];
        a0x = fmaf(ww, v.x, a0x); a0y = fmaf(ww, v.y, a0y);
    }
    float accx = (a0x + a1x) + (a2x + a3x);
    float accy = (a0y + a1y) + (a2y + a3y);
    float dn = dis[n];
    float2 hv = *(const float2*)&h[(size_t)n * 128 + lane * 2];
    float2 o;
    o.x = fmaxf(dn * (accx + dn * hv.x) + bias[lane * 2], 0.f);
    o.y = fmaxf(dn * (accy + dn * hv.y) + bias[lane * 2 + 1], 0.f);
    *(float2*)&out[(size_t)n * 128 + lane * 2] = o;
}

// one wave per dst node, lanes across 64 features; fused self-loop+bias (no relu)
__global__ __launch_bounds__(256) void gather64(
    const int* __restrict__ rp, const int* __restrict__ csr,
    const float* __restrict__ dis, const float* __restrict__ h,
    const float* __restrict__ bias, float* __restrict__ out, int Nn) {
    int n = (blockIdx.x * 256 + threadIdx.x) >> 6;
    int lane = threadIdx.x & 63;
    if (n >= Nn) return;
    int beg = rp[n], end = rp[n + 1];
    float a0 = 0.f, a1 = 0.f, a2 = 0.f, a3 = 0.f;
    int j = beg;
    for (; j + 3 < end; j += 4) {
        int s0 = csr[j], s1 = csr[j + 1], s2 = csr[j + 2], s3 = csr[j + 3];
        float w0 = dis[s0], w1 = dis[s1], w2 = dis[s2], w3 = dis[s3];
        float v0 = h[(size_t)s0 * 64 + lane];
        float v1 = h[(size_t)s1 * 64 + lane];
        float v2 = h[(size_t)s2 * 64 + lane];
        float v3 = h[(size_t)s3 * 64 + lane];
        a0 = fmaf(w0, v0, a0); a1 = fmaf(w1, v1, a1);
        a2 = fmaf(w2, v2, a2); a3 = fmaf(w3, v3, a3);
    }
    for (; j < end; j++) {
        int s = csr[j];
        a0 = fmaf(dis[s], h[(size_t)s * 64 + lane], a0);
    }
    float acc = (a0 + a1) + (a2 + a3);
    float dn = dis[n];
    float hv = h[(size_t)n * 64 + lane];
    out[(size_t)n * 64 + lane] = dn * (acc + dn * hv) + bias[lane];
}

extern "C" void kernel_launch(void* const* d_in, const int* in_sizes, int n_in,
                              void* d_out, int out_size, void* d_ws, size_t ws_size,
                              hipStream_t stream) {
    const float* x  = (const float*)d_in[0];
    const int*   ei = (const int*)d_in[1];
    const float* W1 = (const float*)d_in[2];
    const float* b1 = (const float*)d_in[3];
    const float* W2 = (const float*)d_in[4];
    const float* b2 = (const float*)d_in[5];

    const int IN = 500, H = 128, OUT = 64;
    const int Nn = in_sizes[0] / IN;     // 50000
    const int E  = in_sizes[1] / 2;      // 800000
    const int* src  = ei;
    const int* dstp = ei + E;

    const int Npad = ((Nn + 63) / 64) * 64;
    const int nb   = (Nn + 255) / 256;
    const int K1p  = 512, K2p = 128;

    // workspace layout (int units)
    int*   degdis  = (int*)d_ws;                 // N: int deg -> float dis in place
    int*   rp      = degdis + Npad;              // N+1
    int*   bsum    = rp + Npad + 64;             // 1024
    int*   boff    = bsum + 1024;                // 1024
    int*   cursor  = boff + 1024;                // N
    int*   csr_src = cursor + Npad;              // E
    unsigned short* Bt1h = (unsigned short*)(csr_src + ((E + 63) / 64) * 64);  // 128*512
    unsigned short* Bt1l = Bt1h + H * K1p;
    unsigned short* Bt2h = Bt1l + H * K1p;       // 64*128
    unsigned short* Bt2l = Bt2h + OUT * K2p;
    float* h1      = (float*)(Bt2l + OUT * K2p);
    float* agg1    = h1 + (size_t)Nn * H;
    float* h2      = h1;                         // reuse after layer-1 gather
    float* dis     = (float*)degdis;
    float* out     = (float*)d_out;

    // ---- degree / CSR build ----
    fill_int<<<(Nn + 255) / 256, 256, 0, stream>>>(degdis, 0, Nn);
    deg_accum_i<<<(E + 255) / 256, 256, 0, stream>>>(dstp, degdis, E);
    scan_part<<<nb, 256, 0, stream>>>(degdis, bsum, Nn);
    scan_top<<<1, 1024, 0, stream>>>(bsum, nb, boff, rp, Nn);
    scan_final<<<nb, 256, 0, stream>>>(degdis, boff, rp, cursor, Nn);
    make_dis<<<(Nn + 255) / 256, 256, 0, stream>>>(degdis, Nn);
    csr_fill<<<(E + 255) / 256, 256, 0, stream>>>(src, dstp, cursor, csr_src, E);

    // ---- weight prep (bf16 hi/lo, transposed) ----
    prep_b<<<(H * K1p + 255) / 256, 256, 0, stream>>>(W1, Bt1h, Bt1l, IN, H, K1p);
    prep_b<<<(OUT * K2p + 255) / 256, 256, 0, stream>>>(W2, Bt2h, Bt2l, H, OUT, K2p);

    // ---- layer 1: BM=32, BN=128, NG=16; LDS 20.5KB, grid 1563 ----
    gemm_occ<128, 16><<<(Nn + 31) / 32, 256, 0, stream>>>(x, Bt1h, Bt1l, h1, Nn, IN, K1p);
    gather128<<<(Nn + 3) / 4, 256, 0, stream>>>(rp, csr_src, dis, h1, b1, agg1, Nn);

    // ---- layer 2: BM=32, BN=64, NG=4; LDS 10.2KB, grid 1563 ----
    gemm_occ<64, 4><<<(Nn + 31) / 32, 256, 0, stream>>>(agg1, Bt2h, Bt2l, h2, Nn, H, K2p);
    gather64<<<(Nn + 3) / 4, 256, 0, stream>>>(rp, csr_src, dis, h2, b2, out, Nn);
}

// Round 12
// 261.917 us; speedup vs baseline: 1.3215x; 1.3215x over previous
//
#include <hip/hip_runtime.h>
#include <hip/hip_bf16.h>

// GCN 2-layer encoder. CSR-gather aggregation + split-bf16 MFMA GEMMs.
// r12: gemm = r6's proven register-preload structure (80us). Gathers redesigned for
// memory-level parallelism: half/quarter-wave float4, 8 rows in flight per wave.

typedef __attribute__((ext_vector_type(4))) float f32x4;
typedef __attribute__((ext_vector_type(8))) short short8;
typedef __attribute__((ext_vector_type(8))) unsigned short u16x8;

static __device__ __forceinline__ unsigned short f2bf(float f) {
    unsigned int u = __float_as_uint(f);
    u += 0x7FFF + ((u >> 16) & 1);          // round-to-nearest-even
    return (unsigned short)(u >> 16);
}
static __device__ __forceinline__ float bf2f(unsigned short h) {
    return __uint_as_float(((unsigned int)h) << 16);
}

__global__ void fill_int(int* __restrict__ p, int v, int n) {
    int i = blockIdx.x * blockDim.x + threadIdx.x;
    if (i < n) p[i] = v;
}

__global__ void deg_accum_i(const int* __restrict__ dst, int* __restrict__ deg, int E) {
    int i = blockIdx.x * blockDim.x + threadIdx.x;
    if (i < E) atomicAdd(&deg[dst[i]], 1);
}

// ---- hierarchical exclusive scan: deg[N] -> rp[N+1], cursor[N]; also dis = rsqrt(deg+1) ----
__global__ void scan_part(const int* __restrict__ deg, int* __restrict__ bsum, int N) {
    int tid = threadIdx.x, lane = tid & 63, wid = tid >> 6;
    int i = blockIdx.x * 256 + tid;
    int v = (i < N) ? deg[i] : 0;
#pragma unroll
    for (int off = 1; off < 64; off <<= 1) v += __shfl_xor(v, off, 64);
    __shared__ int ws[4];
    if (lane == 0) ws[wid] = v;
    __syncthreads();
    if (tid == 0) bsum[blockIdx.x] = ws[0] + ws[1] + ws[2] + ws[3];
}

__global__ __launch_bounds__(1024) void scan_top(const int* __restrict__ bsum, int nb,
                                                 int* __restrict__ boff, int* __restrict__ rp, int N) {
    __shared__ int wsum[16];
    int tid = threadIdx.x, lane = tid & 63, wid = tid >> 6;
    int v = (tid < nb) ? bsum[tid] : 0;
    int x = v;
#pragma unroll
    for (int off = 1; off < 64; off <<= 1) {
        int t = __shfl_up(x, off, 64);
        if (lane >= off) x += t;
    }
    if (lane == 63) wsum[wid] = x;
    __syncthreads();
    if (tid < 16) {
        int y = wsum[tid];
#pragma unroll
        for (int off = 1; off < 16; off <<= 1) {
            int t = __shfl_up(y, off, 16);
            if (tid >= off) y += t;
        }
        wsum[tid] = y;
    }
    __syncthreads();
    int base = wid ? wsum[wid - 1] : 0;
    if (tid < nb) boff[tid] = base + x - v;
    if (tid == 0) rp[N] = wsum[15];
}

// fused: scan finalize + cursor init + dis = rsqrt(deg+1) written in place over deg
__global__ void scan_final(int* __restrict__ deg, const int* __restrict__ boff,
                           int* __restrict__ rp, int* __restrict__ cursor, int N) {
    int tid = threadIdx.x, lane = tid & 63, wid = tid >> 6;
    int i = blockIdx.x * 256 + tid;
    int v = (i < N) ? deg[i] : 0;
    int x = v;
#pragma unroll
    for (int off = 1; off < 64; off <<= 1) {
        int t = __shfl_up(x, off, 64);
        if (lane >= off) x += t;
    }
    __shared__ int wsum[4];
    if (lane == 63) wsum[wid] = x;
    __syncthreads();
    int base = boff[blockIdx.x];
    for (int ww = 0; ww < wid; ww++) base += wsum[ww];
    int ex = base + x - v;
    if (i < N) {
        rp[i] = ex;
        cursor[i] = ex;
        ((float*)deg)[i] = rsqrtf((float)(v + 1));   // self loop adds 1
    }
}

__global__ void csr_fill(const int* __restrict__ src, const int* __restrict__ dst,
                         int* __restrict__ cursor, int* __restrict__ csr_src, int E) {
    int e = blockIdx.x * blockDim.x + threadIdx.x;
    if (e < E) {
        int pos = atomicAdd(&cursor[dst[e]], 1);
        csr_src[pos] = src[e];
    }
}

// both weights: f32 [K x N] -> transposed bf16 hi/lo [N][Kpad] (zero-padded past K)
__global__ void prep_both(const float* __restrict__ W1, const float* __restrict__ W2,
                          unsigned short* __restrict__ B1h, unsigned short* __restrict__ B1l,
                          unsigned short* __restrict__ B2h, unsigned short* __restrict__ B2l,
                          int K1, int N1, int K1p, int K2, int N2, int K2p) {
    int idx = blockIdx.x * 256 + threadIdx.x;
    int n1 = N1 * K1p;
    if (idx < n1) {
        int n = idx / K1p, k = idx - n * K1p;
        float v = (k < K1) ? W1[(size_t)k * N1 + n] : 0.f;
        unsigned short h = f2bf(v);
        B1h[idx] = h;
        B1l[idx] = f2bf(v - bf2f(h));
    } else {
        int idx2 = idx - n1;
        if (idx2 < N2 * K2p) {
            int n = idx2 / K2p, k = idx2 - n * K2p;
            float v = (k < K2) ? W2[(size_t)k * N2 + n] : 0.f;
            unsigned short h = f2bf(v);
            B2h[idx2] = h;
            B2l[idx2] = f2bf(v - bf2f(h));
        }
    }
}

// C[M x BN] = A[M x K] @ B[K x BN], split-bf16 MFMA (r6 structure, measured 80us L1).
// BM=32, BK=32, KT = Kpad/32 K-tiles. A preloaded to registers (areg[KT], one float4
// per thread per tile); in-loop global traffic is only B (L2-resident weights).
template<int BN, int KT, int WROWS, int WCOLS>
__global__ __launch_bounds__(256) void gemm_mfma(
    const float* __restrict__ A, const unsigned short* __restrict__ Bth,
    const unsigned short* __restrict__ Btl, float* __restrict__ C,
    int M, int K, int Kpad) {
    constexpr int BM = 32, BK = 32, STR = BK + 8;
    constexpr int MF = (BM / WROWS) / 16;
    constexpr int NF = (BN / WCOLS) / 16;
    constexpr int TPB = 256 / BN;            // threads per B row
    constexpr int BCH = BK / TPB;            // ushorts per thread (B)
    constexpr int NV = BCH / 8;              // u16x8 vectors per thread (B)
    static_assert(BN * TPB == 256 && NV >= 1, "B staging mapping");

    __shared__ unsigned short AsH[BM][STR], AsL[BM][STR];
    __shared__ unsigned short BsH[BN][STR], BsL[BN][STR];

    const int tid = threadIdx.x;
    const int lane = tid & 63;
    const int w = tid >> 6;
    const int wrow = (w / WCOLS) * (BM / WROWS);
    const int wcol = (w % WCOLS) * (BN / WCOLS);
    const int bm = blockIdx.x * BM;
    const int lrow = lane & 15;
    const int lkq = (lane >> 4) * 8;
    const int ar = tid >> 3;                 // A row (32 rows, 8 thr/row)
    const int ak = (tid & 7) << 2;           // A k-offset within tile
    const int bn = tid / TPB;
    const int bkoff = (tid % TPB) * BCH;

    f32x4 acc[MF][NF] = {};

    // ---- preload ALL of A for this block's 32 rows into registers ----
    float4 areg[KT];
    {
        const int arow = bm + ar;
        const bool rok = arow < M;
        const float* rowp = &A[(size_t)arow * K];
#pragma unroll
        for (int kt = 0; kt < KT; kt++) {
            int kg = kt * 32 + ak;
            float4 v = make_float4(0.f, 0.f, 0.f, 0.f);
            if (rok) {
                if (kg + 3 < K) v = *(const float4*)&rowp[kg];
                else {
                    if (kg     < K) v.x = rowp[kg];
                    if (kg + 1 < K) v.y = rowp[kg + 1];
                    if (kg + 2 < K) v.z = rowp[kg + 2];
                }
            }
            areg[kt] = v;
        }
    }

    u16x8 bh[NV], bl[NV];
    auto loadB = [&](int kt) {
        const size_t bo = (size_t)bn * Kpad + kt * 32 + bkoff;
#pragma unroll
        for (int v = 0; v < NV; v++) {
            bh[v] = *(const u16x8*)&Bth[bo + v * 8];
            bl[v] = *(const u16x8*)&Btl[bo + v * 8];
        }
    };
    loadB(0);

    for (int kt = 0; kt < KT; kt++) {
        {
            float4 v = areg[kt];
            ushort4 h4, l4;
            h4.x = f2bf(v.x); l4.x = f2bf(v.x - bf2f(h4.x));
            h4.y = f2bf(v.y); l4.y = f2bf(v.y - bf2f(h4.y));
            h4.z = f2bf(v.z); l4.z = f2bf(v.z - bf2f(h4.z));
            h4.w = f2bf(v.w); l4.w = f2bf(v.w - bf2f(h4.w));
            *(ushort4*)&AsH[ar][ak] = h4;
            *(ushort4*)&AsL[ar][ak] = l4;
        }
#pragma unroll
        for (int v = 0; v < NV; v++) {
            *(u16x8*)&BsH[bn][bkoff + v * 8] = bh[v];
            *(u16x8*)&BsL[bn][bkoff + v * 8] = bl[v];
        }
        __syncthreads();
        if (kt + 1 < KT) loadB(kt + 1);      // L2-resident weight prefetch
        short8 ah[MF], al[MF], bhf[NF], blf[NF];
#pragma unroll
        for (int m = 0; m < MF; m++) {
            ah[m] = *(const short8*)&AsH[wrow + m * 16 + lrow][lkq];
            al[m] = *(const short8*)&AsL[wrow + m * 16 + lrow][lkq];
        }
#pragma unroll
        for (int n = 0; n < NF; n++) {
            bhf[n] = *(const short8*)&BsH[wcol + n * 16 + lrow][lkq];
            blf[n] = *(const short8*)&BsL[wcol + n * 16 + lrow][lkq];
        }
#pragma unroll
        for (int m = 0; m < MF; m++)
#pragma unroll
            for (int n = 0; n < NF; n++) {
                acc[m][n] = __builtin_amdgcn_mfma_f32_16x16x32_bf16(ah[m], bhf[n], acc[m][n], 0, 0, 0);
                acc[m][n] = __builtin_amdgcn_mfma_f32_16x16x32_bf16(al[m], bhf[n], acc[m][n], 0, 0, 0);
                acc[m][n] = __builtin_amdgcn_mfma_f32_16x16x32_bf16(ah[m], blf[n], acc[m][n], 0, 0, 0);
            }
        __syncthreads();
    }
    // store: C/D layout col=lane&15, row=(lane>>4)*4+q
#pragma unroll
    for (int m = 0; m < MF; m++)
#pragma unroll
        for (int n = 0; n < NF; n++)
#pragma unroll
            for (int q = 0; q < 4; q++) {
                int row = bm + wrow + m * 16 + (lane >> 4) * 4 + q;
                int col = wcol + n * 16 + (lane & 15);
                if (row < M) C[(size_t)row * BN + col] = acc[m][n][q];
            }
}

// gather for F=128: one wave per dst node, HALF-wave (32 lanes x float4) per edge,
// 4 accumulators per half -> 8 rows in flight. Fused self-loop + bias + relu.
__global__ __launch_bounds__(256) void gather128(
    const int* __restrict__ rp, const int* __restrict__ csr,
    const float* __restrict__ dis, const float* __restrict__ h,
    const float* __restrict__ bias, float* __restrict__ out, int Nn) {
    int n = (blockIdx.x * 256 + threadIdx.x) >> 6;
    int lane = threadIdx.x & 63;
    if (n >= Nn) return;
    const int hh = lane >> 5;       // half id (0/1)
    const int l = lane & 31;        // 32 lanes x 4 feats
    int beg = rp[n], end = rp[n + 1];
    float4 a0 = {0,0,0,0}, a1 = {0,0,0,0}, a2 = {0,0,0,0}, a3 = {0,0,0,0};
    auto P = [&](int e, float4& a) {
        int s = csr[e];
        float w = dis[s];
        float4 v = *(const float4*)&h[(size_t)s * 128 + l * 4];
        a.x = fmaf(w, v.x, a.x); a.y = fmaf(w, v.y, a.y);
        a.z = fmaf(w, v.z, a.z); a.w = fmaf(w, v.w, a.w);
    };
    int j = beg + hh;               // this half handles indices == hh (mod 2)
    for (; j + 6 < end; j += 8) { P(j, a0); P(j + 2, a1); P(j + 4, a2); P(j + 6, a3); }
    for (; j < end; j += 2) P(j, a0);
    float4 acc;
    acc.x = (a0.x + a1.x) + (a2.x + a3.x);
    acc.y = (a0.y + a1.y) + (a2.y + a3.y);
    acc.z = (a0.z + a1.z) + (a2.z + a3.z);
    acc.w = (a0.w + a1.w) + (a2.w + a3.w);
    acc.x += __shfl_xor(acc.x, 32);
    acc.y += __shfl_xor(acc.y, 32);
    acc.z += __shfl_xor(acc.z, 32);
    acc.w += __shfl_xor(acc.w, 32);
    float dn = dis[n];
    float4 hv = *(const float4*)&h[(size_t)n * 128 + l * 4];
    float4 b4 = *(const float4*)&bias[l * 4];
    float4 o;
    o.x = fmaxf(dn * (acc.x + dn * hv.x) + b4.x, 0.f);
    o.y = fmaxf(dn * (acc.y + dn * hv.y) + b4.y, 0.f);
    o.z = fmaxf(dn * (acc.z + dn * hv.z) + b4.z, 0.f);
    o.w = fmaxf(dn * (acc.w + dn * hv.w) + b4.w, 0.f);
    if (hh == 0) *(float4*)&out[(size_t)n * 128 + l * 4] = o;
}

// gather for F=64: one wave per dst node, QUARTER-wave (16 lanes x float4) per edge,
// 2 accumulators per quarter -> 8 rows in flight. Fused self-loop + bias (no relu).
__global__ __launch_bounds__(256) void gather64(
    const int* __restrict__ rp, const int* __restrict__ csr,
    const float* __restrict__ dis, const float* __restrict__ h,
    const float* __restrict__ bias, float* __restrict__ out, int Nn) {
    int n = (blockIdx.x * 256 + threadIdx.x) >> 6;
    int lane = threadIdx.x & 63;
    if (n >= Nn) return;
    const int q = lane >> 4;        // quarter id (0..3)
    const int l = lane & 15;        // 16 lanes x 4 feats
    int beg = rp[n], end = rp[n + 1];
    float4 a0 = {0,0,0,0}, a1 = {0,0,0,0};
    auto P = [&](int e, float4& a) {
        int s = csr[e];
        float w = dis[s];
        float4 v = *(const float4*)&h[(size_t)s * 64 + l * 4];
        a.x = fmaf(w, v.x, a.x); a.y = fmaf(w, v.y, a.y);
        a.z = fmaf(w, v.z, a.z); a.w = fmaf(w, v.w, a.w);
    };
    int j = beg + q;                // this quarter handles indices == q (mod 4)
    for (; j + 4 < end; j += 8) { P(j, a0); P(j + 4, a1); }
    for (; j < end; j += 4) P(j, a0);
    float4 acc;
    acc.x = a0.x + a1.x; acc.y = a0.y + a1.y;
    acc.z = a0.z + a1.z; acc.w = a0.w + a1.w;
    acc.x += __shfl_xor(acc.x, 16); acc.x += __shfl_xor(acc.x, 32);
    acc.y += __shfl_xor(acc.y, 16); acc.y += __shfl_xor(acc.y, 32);
    acc.z += __shfl_xor(acc.z, 16); acc.z += __shfl_xor(acc.z, 32);
    acc.w += __shfl_xor(acc.w, 16); acc.w += __shfl_xor(acc.w, 32);
    float dn = dis[n];
    float4 hv = *(const float4*)&h[(size_t)n * 64 + l * 4];
    float4 b4 = *(const float4*)&bias[l * 4];
    float4 o;
    o.x = dn * (acc.x + dn * hv.x) + b4.x;
    o.y = dn * (acc.y + dn * hv.y) + b4.y;
    o.z = dn * (acc.z + dn * hv.z) + b4.z;
    o.w = dn * (acc.w + dn * hv.w) + b4.w;
    if (q == 0) *(float4*)&out[(size_t)n * 64 + l * 4] = o;
}

extern "C" void kernel_launch(void* const* d_in, const int* in_sizes, int n_in,
                              void* d_out, int out_size, void* d_ws, size_t ws_size,
                              hipStream_t stream) {
    const float* x  = (const float*)d_in[0];
    const int*   ei = (const int*)d_in[1];
    const float* W1 = (const float*)d_in[2];
    const float* b1 = (const float*)d_in[3];
    const float* W2 = (const float*)d_in[4];
    const float* b2 = (const float*)d_in[5];

    const int IN = 500, H = 128, OUT = 64;
    const int Nn = in_sizes[0] / IN;     // 50000
    const int E  = in_sizes[1] / 2;      // 800000
    const int* src  = ei;
    const int* dstp = ei + E;

    const int Npad = ((Nn + 63) / 64) * 64;
    const int nb   = (Nn + 255) / 256;
    const int K1p  = 512, K2p = 128;

    // workspace layout (int units)
    int*   degdis  = (int*)d_ws;                 // N: int deg -> float dis in place
    int*   rp      = degdis + Npad;              // N+1
    int*   bsum    = rp + Npad + 64;             // 1024
    int*   boff    = bsum + 1024;                // 1024
    int*   cursor  = boff + 1024;                // N
    int*   csr_src = cursor + Npad;              // E
    unsigned short* Bt1h = (unsigned short*)(csr_src + ((E + 63) / 64) * 64);  // 128*512
    unsigned short* Bt1l = Bt1h + H * K1p;
    unsigned short* Bt2h = Bt1l + H * K1p;       // 64*128
    unsigned short* Bt2l = Bt2h + OUT * K2p;
    float* h1      = (float*)(Bt2l + OUT * K2p);
    float* agg1    = h1 + (size_t)Nn * H;
    float* h2      = h1;                         // reuse after layer-1 gather
    float* dis     = (float*)degdis;
    float* out     = (float*)d_out;

    // ---- degree / CSR build (dis fused into scan_final) ----
    fill_int<<<(Nn + 255) / 256, 256, 0, stream>>>(degdis, 0, Nn);
    deg_accum_i<<<(E + 255) / 256, 256, 0, stream>>>(dstp, degdis, E);
    scan_part<<<nb, 256, 0, stream>>>(degdis, bsum, Nn);
    scan_top<<<1, 1024, 0, stream>>>(bsum, nb, boff, rp, Nn);
    scan_final<<<nb, 256, 0, stream>>>(degdis, boff, rp, cursor, Nn);
    csr_fill<<<(E + 255) / 256, 256, 0, stream>>>(src, dstp, cursor, csr_src, E);

    // ---- weight prep (single launch) ----
    prep_both<<<(H * K1p + OUT * K2p + 255) / 256, 256, 0, stream>>>(
        W1, W2, Bt1h, Bt1l, Bt2h, Bt2l, IN, H, K1p, H, OUT, K2p);

    // ---- layer 1 ----
    gemm_mfma<128, 16, 2, 2><<<(Nn + 31) / 32, 256, 0, stream>>>(x, Bt1h, Bt1l, h1, Nn, IN, K1p);
    gather128<<<(Nn + 3) / 4, 256, 0, stream>>>(rp, csr_src, dis, h1, b1, agg1, Nn);

    // ---- layer 2 ----
    gemm_mfma<64, 4, 2, 2><<<(Nn + 31) / 32, 256, 0, stream>>>(agg1, Bt2h, Bt2l, h2, Nn, H, K2p);
    gather64<<<(Nn + 3) / 4, 256, 0, stream>>>(rp, csr_src, dis, h2, b2, out, Nn);
}

// Round 13
// 218.356 us; speedup vs baseline: 1.5851x; 1.1995x over previous
//
#include <hip/hip_runtime.h>
#include <hip/hip_bf16.h>

// GCN 2-layer encoder. CSR-gather aggregation + split-bf16 MFMA GEMMs.
// r13: h1/h2 stored as bf16 (gather-only consumers) -> gather read bytes halved.
// gemm = r6's proven structure; agg1 (gemm2 input) stays f32.

typedef __attribute__((ext_vector_type(4))) float f32x4;
typedef __attribute__((ext_vector_type(8))) short short8;
typedef __attribute__((ext_vector_type(8))) unsigned short u16x8;

static __device__ __forceinline__ unsigned short f2bf(float f) {
    unsigned int u = __float_as_uint(f);
    u += 0x7FFF + ((u >> 16) & 1);          // round-to-nearest-even
    return (unsigned short)(u >> 16);
}
static __device__ __forceinline__ float bf2f(unsigned short h) {
    return __uint_as_float(((unsigned int)h) << 16);
}

__global__ void deg_accum_i(const int* __restrict__ dst, int* __restrict__ deg, int E) {
    int i = blockIdx.x * blockDim.x + threadIdx.x;
    if (i < E) atomicAdd(&deg[dst[i]], 1);
}

// fused: zero degree array + convert both weights to transposed bf16 hi/lo
__global__ void prep_and_zero(const float* __restrict__ W1, const float* __restrict__ W2,
                              unsigned short* __restrict__ B1h, unsigned short* __restrict__ B1l,
                              unsigned short* __restrict__ B2h, unsigned short* __restrict__ B2l,
                              int* __restrict__ deg, int Nn,
                              int K1, int N1, int K1p, int K2, int N2, int K2p) {
    int idx = blockIdx.x * 256 + threadIdx.x;
    if (idx < Nn) deg[idx] = 0;
    int n1 = N1 * K1p;
    if (idx < n1) {
        int n = idx / K1p, k = idx - n * K1p;
        float v = (k < K1) ? W1[(size_t)k * N1 + n] : 0.f;
        unsigned short h = f2bf(v);
        B1h[idx] = h;
        B1l[idx] = f2bf(v - bf2f(h));
    } else {
        int idx2 = idx - n1;
        if (idx2 < N2 * K2p) {
            int n = idx2 / K2p, k = idx2 - n * K2p;
            float v = (k < K2) ? W2[(size_t)k * N2 + n] : 0.f;
            unsigned short h = f2bf(v);
            B2h[idx2] = h;
            B2l[idx2] = f2bf(v - bf2f(h));
        }
    }
}

// ---- hierarchical exclusive scan: deg[N] -> rp[N+1], cursor[N]; also dis = rsqrt(deg+1) ----
__global__ void scan_part(const int* __restrict__ deg, int* __restrict__ bsum, int N) {
    int tid = threadIdx.x, lane = tid & 63, wid = tid >> 6;
    int i = blockIdx.x * 256 + tid;
    int v = (i < N) ? deg[i] : 0;
#pragma unroll
    for (int off = 1; off < 64; off <<= 1) v += __shfl_xor(v, off, 64);
    __shared__ int ws[4];
    if (lane == 0) ws[wid] = v;
    __syncthreads();
    if (tid == 0) bsum[blockIdx.x] = ws[0] + ws[1] + ws[2] + ws[3];
}

__global__ __launch_bounds__(1024) void scan_top(const int* __restrict__ bsum, int nb,
                                                 int* __restrict__ boff, int* __restrict__ rp, int N) {
    __shared__ int wsum[16];
    int tid = threadIdx.x, lane = tid & 63, wid = tid >> 6;
    int v = (tid < nb) ? bsum[tid] : 0;
    int x = v;
#pragma unroll
    for (int off = 1; off < 64; off <<= 1) {
        int t = __shfl_up(x, off, 64);
        if (lane >= off) x += t;
    }
    if (lane == 63) wsum[wid] = x;
    __syncthreads();
    if (tid < 16) {
        int y = wsum[tid];
#pragma unroll
        for (int off = 1; off < 16; off <<= 1) {
            int t = __shfl_up(y, off, 16);
            if (tid >= off) y += t;
        }
        wsum[tid] = y;
    }
    __syncthreads();
    int base = wid ? wsum[wid - 1] : 0;
    if (tid < nb) boff[tid] = base + x - v;
    if (tid == 0) rp[N] = wsum[15];
}

// fused: scan finalize + cursor init + dis = rsqrt(deg+1) written in place over deg
__global__ void scan_final(int* __restrict__ deg, const int* __restrict__ boff,
                           int* __restrict__ rp, int* __restrict__ cursor, int N) {
    int tid = threadIdx.x, lane = tid & 63, wid = tid >> 6;
    int i = blockIdx.x * 256 + tid;
    int v = (i < N) ? deg[i] : 0;
    int x = v;
#pragma unroll
    for (int off = 1; off < 64; off <<= 1) {
        int t = __shfl_up(x, off, 64);
        if (lane >= off) x += t;
    }
    __shared__ int wsum[4];
    if (lane == 63) wsum[wid] = x;
    __syncthreads();
    int base = boff[blockIdx.x];
    for (int ww = 0; ww < wid; ww++) base += wsum[ww];
    int ex = base + x - v;
    if (i < N) {
        rp[i] = ex;
        cursor[i] = ex;
        ((float*)deg)[i] = rsqrtf((float)(v + 1));   // self loop adds 1
    }
}

__global__ void csr_fill(const int* __restrict__ src, const int* __restrict__ dst,
                         int* __restrict__ cursor, int* __restrict__ csr_src, int E) {
    int e = blockIdx.x * blockDim.x + threadIdx.x;
    if (e < E) {
        int pos = atomicAdd(&cursor[dst[e]], 1);
        csr_src[pos] = src[e];
    }
}

// C[M x BN] = A[M x K] @ B[K x BN], split-bf16 MFMA (r6 structure, measured 80us L1).
// BM=32, BK=32, KT = Kpad/32 K-tiles. A preloaded to registers; output stored as bf16.
template<int BN, int KT, int WROWS, int WCOLS>
__global__ __launch_bounds__(256) void gemm_mfma(
    const float* __restrict__ A, const unsigned short* __restrict__ Bth,
    const unsigned short* __restrict__ Btl, unsigned short* __restrict__ C,
    int M, int K, int Kpad) {
    constexpr int BM = 32, BK = 32, STR = BK + 8;
    constexpr int MF = (BM / WROWS) / 16;
    constexpr int NF = (BN / WCOLS) / 16;
    constexpr int TPB = 256 / BN;            // threads per B row
    constexpr int BCH = BK / TPB;            // ushorts per thread (B)
    constexpr int NV = BCH / 8;              // u16x8 vectors per thread (B)
    static_assert(BN * TPB == 256 && NV >= 1, "B staging mapping");

    __shared__ unsigned short AsH[BM][STR], AsL[BM][STR];
    __shared__ unsigned short BsH[BN][STR], BsL[BN][STR];

    const int tid = threadIdx.x;
    const int lane = tid & 63;
    const int w = tid >> 6;
    const int wrow = (w / WCOLS) * (BM / WROWS);
    const int wcol = (w % WCOLS) * (BN / WCOLS);
    const int bm = blockIdx.x * BM;
    const int lrow = lane & 15;
    const int lkq = (lane >> 4) * 8;
    const int ar = tid >> 3;                 // A row (32 rows, 8 thr/row)
    const int ak = (tid & 7) << 2;           // A k-offset within tile
    const int bn = tid / TPB;
    const int bkoff = (tid % TPB) * BCH;

    f32x4 acc[MF][NF] = {};

    // ---- preload ALL of A for this block's 32 rows into registers ----
    float4 areg[KT];
    {
        const int arow = bm + ar;
        const bool rok = arow < M;
        const float* rowp = &A[(size_t)arow * K];
#pragma unroll
        for (int kt = 0; kt < KT; kt++) {
            int kg = kt * 32 + ak;
            float4 v = make_float4(0.f, 0.f, 0.f, 0.f);
            if (rok) {
                if (kg + 3 < K) v = *(const float4*)&rowp[kg];
                else {
                    if (kg     < K) v.x = rowp[kg];
                    if (kg + 1 < K) v.y = rowp[kg + 1];
                    if (kg + 2 < K) v.z = rowp[kg + 2];
                }
            }
            areg[kt] = v;
        }
    }

    u16x8 bh[NV], bl[NV];
    auto loadB = [&](int kt) {
        const size_t bo = (size_t)bn * Kpad + kt * 32 + bkoff;
#pragma unroll
        for (int v = 0; v < NV; v++) {
            bh[v] = *(const u16x8*)&Bth[bo + v * 8];
            bl[v] = *(const u16x8*)&Btl[bo + v * 8];
        }
    };
    loadB(0);

    for (int kt = 0; kt < KT; kt++) {
        {
            float4 v = areg[kt];
            ushort4 h4, l4;
            h4.x = f2bf(v.x); l4.x = f2bf(v.x - bf2f(h4.x));
            h4.y = f2bf(v.y); l4.y = f2bf(v.y - bf2f(h4.y));
            h4.z = f2bf(v.z); l4.z = f2bf(v.z - bf2f(h4.z));
            h4.w = f2bf(v.w); l4.w = f2bf(v.w - bf2f(h4.w));
            *(ushort4*)&AsH[ar][ak] = h4;
            *(ushort4*)&AsL[ar][ak] = l4;
        }
#pragma unroll
        for (int v = 0; v < NV; v++) {
            *(u16x8*)&BsH[bn][bkoff + v * 8] = bh[v];
            *(u16x8*)&BsL[bn][bkoff + v * 8] = bl[v];
        }
        __syncthreads();
        if (kt + 1 < KT) loadB(kt + 1);      // L2-resident weight prefetch
        short8 ah[MF], al[MF], bhf[NF], blf[NF];
#pragma unroll
        for (int m = 0; m < MF; m++) {
            ah[m] = *(const short8*)&AsH[wrow + m * 16 + lrow][lkq];
            al[m] = *(const short8*)&AsL[wrow + m * 16 + lrow][lkq];
        }
#pragma unroll
        for (int n = 0; n < NF; n++) {
            bhf[n] = *(const short8*)&BsH[wcol + n * 16 + lrow][lkq];
            blf[n] = *(const short8*)&BsL[wcol + n * 16 + lrow][lkq];
        }
#pragma unroll
        for (int m = 0; m < MF; m++)
#pragma unroll
            for (int n = 0; n < NF; n++) {
                acc[m][n] = __builtin_amdgcn_mfma_f32_16x16x32_bf16(ah[m], bhf[n], acc[m][n], 0, 0, 0);
                acc[m][n] = __builtin_amdgcn_mfma_f32_16x16x32_bf16(al[m], bhf[n], acc[m][n], 0, 0, 0);
                acc[m][n] = __builtin_amdgcn_mfma_f32_16x16x32_bf16(ah[m], blf[n], acc[m][n], 0, 0, 0);
            }
        __syncthreads();
    }
    // store bf16: C/D layout col=lane&15, row=(lane>>4)*4+q
#pragma unroll
    for (int m = 0; m < MF; m++)
#pragma unroll
        for (int n = 0; n < NF; n++)
#pragma unroll
            for (int q = 0; q < 4; q++) {
                int row = bm + wrow + m * 16 + (lane >> 4) * 4 + q;
                int col = wcol + n * 16 + (lane & 15);
                if (row < M) C[(size_t)row * BN + col] = f2bf(acc[m][n][q]);
            }
}

// gather for F=128 (bf16 h): one wave per dst node, HALF-wave (32 lanes x 4 bf16) per edge,
// 4 accumulators per half -> 8 rows in flight. Fused self-loop + bias + relu. f32 out.
__global__ __launch_bounds__(256) void gather128(
    const int* __restrict__ rp, const int* __restrict__ csr,
    const float* __restrict__ dis, const unsigned short* __restrict__ h,
    const float* __restrict__ bias, float* __restrict__ out, int Nn) {
    int n = (blockIdx.x * 256 + threadIdx.x) >> 6;
    int lane = threadIdx.x & 63;
    if (n >= Nn) return;
    const int hh = lane >> 5;       // half id (0/1)
    const int l = lane & 31;        // 32 lanes x 4 feats
    int beg = rp[n], end = rp[n + 1];
    float4 a0 = {0,0,0,0}, a1 = {0,0,0,0}, a2 = {0,0,0,0}, a3 = {0,0,0,0};
    auto P = [&](int e, float4& a) {
        int s = csr[e];
        float w = dis[s];
        ushort4 v = *(const ushort4*)&h[(size_t)s * 128 + l * 4];
        a.x = fmaf(w, bf2f(v.x), a.x); a.y = fmaf(w, bf2f(v.y), a.y);
        a.z = fmaf(w, bf2f(v.z), a.z); a.w = fmaf(w, bf2f(v.w), a.w);
    };
    int j = beg + hh;               // this half handles indices == hh (mod 2)
    for (; j + 6 < end; j += 8) { P(j, a0); P(j + 2, a1); P(j + 4, a2); P(j + 6, a3); }
    for (; j < end; j += 2) P(j, a0);
    float4 acc;
    acc.x = (a0.x + a1.x) + (a2.x + a3.x);
    acc.y = (a0.y + a1.y) + (a2.y + a3.y);
    acc.z = (a0.z + a1.z) + (a2.z + a3.z);
    acc.w = (a0.w + a1.w) + (a2.w + a3.w);
    acc.x += __shfl_xor(acc.x, 32);
    acc.y += __shfl_xor(acc.y, 32);
    acc.z += __shfl_xor(acc.z, 32);
    acc.w += __shfl_xor(acc.w, 32);
    float dn = dis[n];
    ushort4 hv = *(const ushort4*)&h[(size_t)n * 128 + l * 4];
    float4 b4 = *(const float4*)&bias[l * 4];
    float4 o;
    o.x = fmaxf(dn * (acc.x + dn * bf2f(hv.x)) + b4.x, 0.f);
    o.y = fmaxf(dn * (acc.y + dn * bf2f(hv.y)) + b4.y, 0.f);
    o.z = fmaxf(dn * (acc.z + dn * bf2f(hv.z)) + b4.z, 0.f);
    o.w = fmaxf(dn * (acc.w + dn * bf2f(hv.w)) + b4.w, 0.f);
    if (hh == 0) *(float4*)&out[(size_t)n * 128 + l * 4] = o;
}

// gather for F=64 (bf16 h): one wave per dst node, QUARTER-wave (16 lanes x 4 bf16) per edge,
// 2 accumulators per quarter -> 8 rows in flight. Fused self-loop + bias (no relu). f32 out.
__global__ __launch_bounds__(256) void gather64(
    const int* __restrict__ rp, const int* __restrict__ csr,
    const float* __restrict__ dis, const unsigned short* __restrict__ h,
    const float* __restrict__ bias, float* __restrict__ out, int Nn) {
    int n = (blockIdx.x * 256 + threadIdx.x) >> 6;
    int lane = threadIdx.x & 63;
    if (n >= Nn) return;
    const int q = lane >> 4;        // quarter id (0..3)
    const int l = lane & 15;        // 16 lanes x 4 feats
    int beg = rp[n], end = rp[n + 1];
    float4 a0 = {0,0,0,0}, a1 = {0,0,0,0};
    auto P = [&](int e, float4& a) {
        int s = csr[e];
        float w = dis[s];
        ushort4 v = *(const ushort4*)&h[(size_t)s * 64 + l * 4];
        a.x = fmaf(w, bf2f(v.x), a.x); a.y = fmaf(w, bf2f(v.y), a.y);
        a.z = fmaf(w, bf2f(v.z), a.z); a.w = fmaf(w, bf2f(v.w), a.w);
    };
    int j = beg + q;                // this quarter handles indices == q (mod 4)
    for (; j + 4 < end; j += 8) { P(j, a0); P(j + 4, a1); }
    for (; j < end; j += 4) P(j, a0);
    float4 acc;
    acc.x = a0.x + a1.x; acc.y = a0.y + a1.y;
    acc.z = a0.z + a1.z; acc.w = a0.w + a1.w;
    acc.x += __shfl_xor(acc.x, 16); acc.x += __shfl_xor(acc.x, 32);
    acc.y += __shfl_xor(acc.y, 16); acc.y += __shfl_xor(acc.y, 32);
    acc.z += __shfl_xor(acc.z, 16); acc.z += __shfl_xor(acc.z, 32);
    acc.w += __shfl_xor(acc.w, 16); acc.w += __shfl_xor(acc.w, 32);
    float dn = dis[n];
    ushort4 hv = *(const ushort4*)&h[(size_t)n * 64 + l * 4];
    float4 b4 = *(const float4*)&bias[l * 4];
    float4 o;
    o.x = dn * (acc.x + dn * bf2f(hv.x)) + b4.x;
    o.y = dn * (acc.y + dn * bf2f(hv.y)) + b4.y;
    o.z = dn * (acc.z + dn * bf2f(hv.z)) + b4.z;
    o.w = dn * (acc.w + dn * bf2f(hv.w)) + b4.w;
    if (q == 0) *(float4*)&out[(size_t)n * 64 + l * 4] = o;
}

extern "C" void kernel_launch(void* const* d_in, const int* in_sizes, int n_in,
                              void* d_out, int out_size, void* d_ws, size_t ws_size,
                              hipStream_t stream) {
    const float* x  = (const float*)d_in[0];
    const int*   ei = (const int*)d_in[1];
    const float* W1 = (const float*)d_in[2];
    const float* b1 = (const float*)d_in[3];
    const float* W2 = (const float*)d_in[4];
    const float* b2 = (const float*)d_in[5];

    const int IN = 500, H = 128, OUT = 64;
    const int Nn = in_sizes[0] / IN;     // 50000
    const int E  = in_sizes[1] / 2;      // 800000
    const int* src  = ei;
    const int* dstp = ei + E;

    const int Npad = ((Nn + 63) / 64) * 64;
    const int nb   = (Nn + 255) / 256;
    const int K1p  = 512, K2p = 128;

    // workspace layout (int units)
    int*   degdis  = (int*)d_ws;                 // N: int deg -> float dis in place
    int*   rp      = degdis + Npad;              // N+1
    int*   bsum    = rp + Npad + 64;             // 1024
    int*   boff    = bsum + 1024;                // 1024
    int*   cursor  = boff + 1024;                // N
    int*   csr_src = cursor + Npad;              // E
    unsigned short* Bt1h = (unsigned short*)(csr_src + ((E + 63) / 64) * 64);  // 128*512
    unsigned short* Bt1l = Bt1h + H * K1p;
    unsigned short* Bt2h = Bt1l + H * K1p;       // 64*128
    unsigned short* Bt2l = Bt2h + OUT * K2p;
    unsigned short* h1u  = Bt2l + OUT * K2p;     // N*128 bf16
    float* agg1    = (float*)(h1u + (size_t)Nn * H);  // N*128 f32
    unsigned short* h2u  = h1u;                  // reuse after layer-1 gather
    float* dis     = (float*)degdis;
    float* out     = (float*)d_out;

    // ---- degree zero + weight prep (single launch) ----
    prep_and_zero<<<(H * K1p + OUT * K2p + 255) / 256, 256, 0, stream>>>(
        W1, W2, Bt1h, Bt1l, Bt2h, Bt2l, degdis, Nn, IN, H, K1p, H, OUT, K2p);
    deg_accum_i<<<(E + 255) / 256, 256, 0, stream>>>(dstp, degdis, E);
    scan_part<<<nb, 256, 0, stream>>>(degdis, bsum, Nn);
    scan_top<<<1, 1024, 0, stream>>>(bsum, nb, boff, rp, Nn);
    scan_final<<<nb, 256, 0, stream>>>(degdis, boff, rp, cursor, Nn);
    csr_fill<<<(E + 255) / 256, 256, 0, stream>>>(src, dstp, cursor, csr_src, E);

    // ---- layer 1 ----
    gemm_mfma<128, 16, 2, 2><<<(Nn + 31) / 32, 256, 0, stream>>>(x, Bt1h, Bt1l, h1u, Nn, IN, K1p);
    gather128<<<(Nn + 3) / 4, 256, 0, stream>>>(rp, csr_src, dis, h1u, b1, agg1, Nn);

    // ---- layer 2 ----
    gemm_mfma<64, 4, 2, 2><<<(Nn + 31) / 32, 256, 0, stream>>>(agg1, Bt2h, Bt2l, h2u, Nn, H, K2p);
    gather64<<<(Nn + 3) / 4, 256, 0, stream>>>(rp, csr_src, dis, h2u, b2, out, Nn);
}